// Round 6
// baseline (356.963 us; speedup 1.0000x reference)
//
#include <hip/hip_runtime.h>
#include <hip/hip_bf16.h>

// SupPixPool: out[b,c,k] = max over pixels p with spx[b,p]==k of img[b,c,p].
// B=4, C=64, H=W=512, K=1024.
//
// Round-6: wave-per-channel remap. Each wave owns ONE channel stream and its
// 64 lanes load 64 consecutive float4 (1 KB contiguous per instruction);
// spx is likewise 1 KB contiguous per wave-instr (8x reused across c-waves
// via L1/L2). Depth-2 register pipeline keeps 2 loads in flight ahead of the
// LDS atomics. Table stays stride-9 padded; partials dumped UNpadded.
// This isolates hypothesis (a) VMEM-pattern-bound vs (b) LDS-atomic-bound:
// flat result => atomic-RMW pipe is the structural floor.

constexpr int Kseg = 1024;
constexpr int Bn   = 4;
constexpr int Cn   = 64;
constexpr int HWn  = 512 * 512;

constexpr int CH     = 8;             // channels per block
constexpr int NCG    = Cn / CH;       // 8
constexpr int TPB    = 1024;          // 16 waves
constexpr int NCHUNK = 16;            // pixel chunks per (b, cg)
constexpr int PIX    = HWn / NCHUNK;  // 16384 pixels per block
constexpr int STR    = 9;             // padded table stride (36 KB)
constexpr int TBLW   = Kseg * STR;    // 9216 words
constexpr int PARTW  = Kseg * CH;     // 8192 words dumped (unpadded)
constexpr int NBLK   = Bn * NCG * NCHUNK;  // 512
constexpr int QSTEP  = 128;           // quads consumed per block-iteration
constexpr int ITERS  = PIX / (4 * QSTEP);  // 32

typedef float  vf4 __attribute__((ext_vector_type(4)));
typedef int    vi4 __attribute__((ext_vector_type(4)));

// order-preserving float->uint encoding: enc monotonic, unsigned max == fmax
constexpr unsigned ENEG = 0x007FFFFFu;  // enc(-inf)

__device__ __forceinline__ unsigned enc(float f) {
    unsigned u = __float_as_uint(f);
    return u ^ ((unsigned)((int)u >> 31) | 0x80000000u);
}
__device__ __forceinline__ float dec(unsigned e) {
    unsigned u = (e & 0x80000000u) ? (e ^ 0x80000000u) : ~e;
    return __uint_as_float(u);
}

__global__ __launch_bounds__(TPB, 8) void pool_partial(
    const float* __restrict__ img, const int* __restrict__ spx,
    unsigned* __restrict__ part) {
    __shared__ unsigned tbl[TBLW];  // 36 KB, [k][9] padded

    const int bx    = blockIdx.x;
    const int chunk = bx % NCHUNK;
    const int cg    = (bx / NCHUNK) % NCG;
    const int b     = bx / (NCHUNK * NCG);

    for (int i = threadIdx.x; i < TBLW; i += TPB) tbl[i] = ENEG;
    __syncthreads();

    const int wave = threadIdx.x >> 6;
    const int lane = threadIdx.x & 63;
    const int c    = wave & (CH - 1);   // channel owned by this wave
    const int h    = wave >> 3;         // which half of each 128-quad stripe

    const float* imgc = img + ((size_t)(b * Cn + cg * CH + c)) * HWn
                            + (size_t)chunk * PIX;
    const int*   spxb = spx + (size_t)b * HWn + (size_t)chunk * PIX;

    const int q0 = h * 64 + lane;  // quad index base; +128 per iteration

    // depth-2 pipeline: two loads in flight ahead of the atomics
    vf4 v0 = __builtin_nontemporal_load((const vf4*)(imgc + 4 * q0));
    vi4 k0 = *(const vi4*)(spxb + 4 * q0);
    vf4 v1 = __builtin_nontemporal_load((const vf4*)(imgc + 4 * (q0 + QSTEP)));
    vi4 k1 = *(const vi4*)(spxb + 4 * (q0 + QSTEP));

#pragma unroll 4
    for (int it = 0; it < ITERS; ++it) {
        vf4 vn;
        vi4 kn;
        if (it + 2 < ITERS) {
            const int qn = q0 + (it + 2) * QSTEP;
            vn = __builtin_nontemporal_load((const vf4*)(imgc + 4 * qn));
            kn = *(const vi4*)(spxb + 4 * qn);
        }
        atomicMax(tbl + ((k0.x & (Kseg - 1)) * STR + c), enc(v0.x));
        atomicMax(tbl + ((k0.y & (Kseg - 1)) * STR + c), enc(v0.y));
        atomicMax(tbl + ((k0.z & (Kseg - 1)) * STR + c), enc(v0.z));
        atomicMax(tbl + ((k0.w & (Kseg - 1)) * STR + c), enc(v0.w));
        v0 = v1; k0 = k1;
        v1 = vn; k1 = kn;
    }
    __syncthreads();

    // dump unpadded: entry index i = k*CH + j  <-  tbl[k*STR + j]
    unsigned* dst = part + (size_t)bx * PARTW;
    for (int i = threadIdx.x; i < PARTW; i += TPB) {
        const int k = i >> 3, j = i & (CH - 1);
        dst[i] = tbl[k * STR + j];
    }
}

__global__ __launch_bounds__(256) void pool_reduce(
    const unsigned* __restrict__ part, float* __restrict__ out) {
    const int gid = blockIdx.x * 256 + threadIdx.x;  // [0, B*C*K)
    const int k  = gid & (Kseg - 1);
    const int cc = (gid >> 10) & (Cn - 1);
    const int b  = gid >> 16;
    const int cg = cc >> 3, j = cc & (CH - 1);

    unsigned acc = ENEG;
    const unsigned* p = part
        + ((size_t)(b * NCG + cg) * NCHUNK) * PARTW + k * CH + j;
    for (int ch = 0; ch < NCHUNK; ++ch)
        acc = max(acc, p[(size_t)ch * PARTW]);
    out[gid] = dec(acc);
}

// -------- fallback path (ws too small): global atomic merge into d_out -----
__global__ __launch_bounds__(256) void init_enc_k(unsigned* __restrict__ o) {
    o[blockIdx.x * 256 + threadIdx.x] = ENEG;
}

__global__ __launch_bounds__(TPB, 8) void pool_atomic(
    const float* __restrict__ img, const int* __restrict__ spx,
    unsigned* __restrict__ gtab) {
    __shared__ unsigned tbl[TBLW];

    const int bx    = blockIdx.x;
    const int chunk = bx % NCHUNK;
    const int cg    = (bx / NCHUNK) % NCG;
    const int b     = bx / (NCHUNK * NCG);

    for (int i = threadIdx.x; i < TBLW; i += TPB) tbl[i] = ENEG;
    __syncthreads();

    const int wave = threadIdx.x >> 6;
    const int lane = threadIdx.x & 63;
    const int c    = wave & (CH - 1);
    const int h    = wave >> 3;

    const float* imgc = img + ((size_t)(b * Cn + cg * CH + c)) * HWn
                            + (size_t)chunk * PIX;
    const int*   spxb = spx + (size_t)b * HWn + (size_t)chunk * PIX;

    const int q0 = h * 64 + lane;

#pragma unroll 4
    for (int it = 0; it < ITERS; ++it) {
        const int q = q0 + it * QSTEP;
        const vf4 v = *(const vf4*)(imgc + 4 * q);
        vi4 k = *(const vi4*)(spxb + 4 * q);
        atomicMax(tbl + ((k.x & (Kseg - 1)) * STR + c), enc(v.x));
        atomicMax(tbl + ((k.y & (Kseg - 1)) * STR + c), enc(v.y));
        atomicMax(tbl + ((k.z & (Kseg - 1)) * STR + c), enc(v.z));
        atomicMax(tbl + ((k.w & (Kseg - 1)) * STR + c), enc(v.w));
    }
    __syncthreads();

    // tbl[k*STR + j] -> out index (b*Cn + cg*CH + j)*K + k
    unsigned* base = gtab + (size_t)(b * Cn + cg * CH) * Kseg;
    for (int i = threadIdx.x; i < Kseg * CH; i += TPB) {
        const int k = i >> 3, j = i & (CH - 1);
        atomicMax(base + (size_t)j * Kseg + k, tbl[k * STR + j]);
    }
}

__global__ __launch_bounds__(256) void decode_inplace(unsigned* __restrict__ o) {
    const int i = blockIdx.x * 256 + threadIdx.x;
    const unsigned e = o[i];
    ((float*)o)[i] = dec(e);
}

extern "C" void kernel_launch(void* const* d_in, const int* in_sizes, int n_in,
                              void* d_out, int out_size, void* d_ws, size_t ws_size,
                              hipStream_t stream) {
    const float* img = (const float*)d_in[0];
    const int*   spx = (const int*)d_in[1];
    float*       out = (float*)d_out;

    const size_t need = (size_t)NBLK * PARTW * sizeof(unsigned);  // ~16.8 MB
    const int nOut256 = (Bn * Cn * Kseg) / 256;                   // 1024

    if (ws_size >= need) {
        unsigned* part = (unsigned*)d_ws;
        pool_partial<<<NBLK, TPB, 0, stream>>>(img, spx, part);
        pool_reduce<<<nOut256, 256, 0, stream>>>(part, out);
    } else {
        unsigned* gt = (unsigned*)d_out;
        init_enc_k<<<nOut256, 256, 0, stream>>>(gt);
        pool_atomic<<<NBLK, TPB, 0, stream>>>(img, spx, gt);
        decode_inplace<<<nOut256, 256, 0, stream>>>(gt);
    }
}